// Round 2
// baseline (107.887 us; speedup 1.0000x reference)
//
#include <hip/hip_runtime.h>

// WaveKANLinear: out[n,o] = sum_d mexhat((ln(x)[n,d]-t[o,d])/s[o,d]) * ww[o,d]
//                           + silu(sum_d x[n,d]*bw[o,d])
// N=8192, D=128, O=128, ALL float32 (per reference setup_inputs dtypes).
// VALU-bound: 134M exp evals. clip(+-10) is dead: |mexhat| <= 0.8673.

#define D_DIM 128
#define O_DIM 128
#define ROWS  16     // rows per block
#define BLOCK 256    // threads: o = tid&127, row-group g = tid>>7 (8 rows each)

#define MEX_C          0.86732507f     // 2/(sqrt(3)*pi^0.25)
#define NEG_HALF_LOG2E (-0.72134752f)  // -0.5 * log2(e)
#define LOG2E          1.44269504f

// Prep: transpose weights to [d][o] float4 {t*inv_s, inv_s, ww*C, bw}
__global__ __launch_bounds__(256) void wavekan_prep(
    const float* __restrict__ scale,
    const float* __restrict__ trans,
    const float* __restrict__ ww,
    const float* __restrict__ bw,
    float4* __restrict__ wsW)
{
    int idx = blockIdx.x * blockDim.x + threadIdx.x;   // = o*128 + d
    if (idx >= O_DIM * D_DIM) return;
    int o = idx >> 7;
    int d = idx & (D_DIM - 1);
    float sc = scale[idx];
    // numerically stable softplus
    float sp = fmaxf(sc, 0.0f) + log1pf(__expf(-fabsf(sc)));
    float inv_s = 1.0f / (sp + 0.1f);
    float4 w;
    w.x = trans[idx] * inv_s;     // pre-scaled translation
    w.y = inv_s;
    w.z = ww[idx] * MEX_C;
    w.w = bw[idx];
    wsW[d * O_DIM + o] = w;
}

template<bool USE_WS>
__global__ __launch_bounds__(BLOCK) void wavekan_main(
    const float* __restrict__ x,
    const float* __restrict__ scale,
    const float* __restrict__ trans,
    const float* __restrict__ ww,
    const float* __restrict__ bw,
    const float* __restrict__ gamma,
    const float* __restrict__ beta,
    const float4* __restrict__ wsW,
    float* __restrict__ out,
    int N)
{
    __shared__ float s_ln[ROWS * D_DIM];   // layernormed x
    __shared__ float s_raw[ROWS * D_DIM];  // raw x (for base path)

    const int tid  = threadIdx.x;
    const int row0 = blockIdx.x * ROWS;

    // ---- Phase 1: load 16 rows, LayerNorm, stage in LDS ----
    {
        const int r  = tid >> 4;        // local row 0..15
        const int j  = tid & 15;        // 16 lanes per row
        const int d0 = j * 8;           // 8 elems per lane
        const int grow = row0 + r;

        float v[8];
        if (grow < N) {
            const float4* p = reinterpret_cast<const float4*>(x + (size_t)grow * D_DIM + d0);
            float4 a = p[0], b = p[1];
            v[0]=a.x; v[1]=a.y; v[2]=a.z; v[3]=a.w;
            v[4]=b.x; v[5]=b.y; v[6]=b.z; v[7]=b.w;
        } else {
            #pragma unroll
            for (int k = 0; k < 8; ++k) v[k] = 0.0f;
        }

        float sum = 0.0f, ssq = 0.0f;
        #pragma unroll
        for (int k = 0; k < 8; ++k) { sum += v[k]; ssq += v[k] * v[k]; }
        #pragma unroll
        for (int m = 1; m < 16; m <<= 1) {
            sum += __shfl_xor(sum, m, 64);
            ssq += __shfl_xor(ssq, m, 64);
        }
        const float mean = sum * (1.0f / D_DIM);
        const float var  = ssq * (1.0f / D_DIM) - mean * mean;
        const float rstd = rsqrtf(var + 1e-5f);

        const float4* pg = reinterpret_cast<const float4*>(gamma + d0);
        const float4* pb = reinterpret_cast<const float4*>(beta + d0);
        float4 g0 = pg[0], g1 = pg[1], b0 = pb[0], b1 = pb[1];
        float g[8] = {g0.x,g0.y,g0.z,g0.w,g1.x,g1.y,g1.z,g1.w};
        float b[8] = {b0.x,b0.y,b0.z,b0.w,b1.x,b1.y,b1.z,b1.w};

        #pragma unroll
        for (int k = 0; k < 8; ++k) {
            s_ln [r * D_DIM + d0 + k] = (v[k] - mean) * rstd * g[k] + b[k];
            s_raw[r * D_DIM + d0 + k] = v[k];
        }
    }
    __syncthreads();

    // ---- Phase 2: per-thread = one output column o x 8 rows ----
    const int o = tid & (O_DIM - 1);
    const int g = tid >> 7;  // row-group 0/1
    const float* __restrict__ ln  = s_ln  + g * 8 * D_DIM;
    const float* __restrict__ raw = s_raw + g * 8 * D_DIM;

    float accw[8], accb[8];
    #pragma unroll
    for (int k = 0; k < 8; ++k) { accw[k] = 0.0f; accb[k] = 0.0f; }

    #pragma unroll 2
    for (int d = 0; d < D_DIM; ++d) {
        float tws, is, wwc, bwv;
        if (USE_WS) {
            float4 w = wsW[d * O_DIM + o];   // coalesced 16B/lane, L2-resident
            tws = w.x; is = w.y; wwc = w.z; bwv = w.w;
        } else {
            // fallback: direct (uncoalesced) reads, softplus on the fly
            int idx = o * D_DIM + d;
            float sc = scale[idx];
            float sp = fmaxf(sc, 0.0f) + log1pf(__expf(-fabsf(sc)));
            is  = 1.0f / (sp + 0.1f);
            tws = trans[idx] * is;
            wwc = ww[idx] * MEX_C;
            bwv = bw[idx];
        }
        #pragma unroll
        for (int k = 0; k < 8; ++k) {
            float xl = ln[k * D_DIM + d];    // LDS broadcast (wave-uniform addr)
            float z  = fmaf(xl, is, -tws);
            float z2 = z * z;
            float e  = __builtin_amdgcn_exp2f(z2 * NEG_HALF_LOG2E);
            accw[k]  = fmaf((z2 - 1.0f) * e, wwc, accw[k]);
            accb[k]  = fmaf(raw[k * D_DIM + d], bwv, accb[k]);
        }
    }

    // ---- Epilogue: out = wavelet + silu(base) ----
    #pragma unroll
    for (int k = 0; k < 8; ++k) {
        const int rr = row0 + g * 8 + k;
        if (rr < N) {
            float bsum = accb[k];
            float sig  = 1.0f / (1.0f + __builtin_amdgcn_exp2f(-LOG2E * bsum));
            out[(size_t)rr * O_DIM + o] = accw[k] + bsum * sig;
        }
    }
}

extern "C" void kernel_launch(void* const* d_in, const int* in_sizes, int n_in,
                              void* d_out, int out_size, void* d_ws, size_t ws_size,
                              hipStream_t stream) {
    const float* x     = (const float*)d_in[0];
    const float* scale = (const float*)d_in[1];
    const float* trans = (const float*)d_in[2];
    const float* ww    = (const float*)d_in[3];
    const float* bw    = (const float*)d_in[4];
    const float* gamma = (const float*)d_in[5];
    const float* beta  = (const float*)d_in[6];
    float* out = (float*)d_out;

    const int N = in_sizes[0] / D_DIM;       // 8192
    const int grid = (N + ROWS - 1) / ROWS;  // 512

    const size_t ws_needed = (size_t)O_DIM * D_DIM * sizeof(float4);  // 256 KB
    if (ws_size >= ws_needed) {
        wavekan_prep<<<(O_DIM * D_DIM + 255) / 256, 256, 0, stream>>>(
            scale, trans, ww, bw, (float4*)d_ws);
        wavekan_main<true><<<grid, BLOCK, 0, stream>>>(
            x, scale, trans, ww, bw, gamma, beta, (const float4*)d_ws, out, N);
    } else {
        wavekan_main<false><<<grid, BLOCK, 0, stream>>>(
            x, scale, trans, ww, bw, gamma, beta, nullptr, out, N);
    }
}

// Round 3
// 99.395 us; speedup vs baseline: 1.0854x; 1.0854x over previous
//
#include <hip/hip_runtime.h>

// WaveKANLinear: out[n,o] = sum_d mexhat((ln(x)[n,d]-t[o,d])/s[o,d]) * ww[o,d]
//                           + silu(sum_d x[n,d]*bw[o,d])
// N=8192, D=128, O=128, float32. VALU-bound: 134M exp evals.
// clip(+-10) dead: |mexhat| <= 0.8673.
//
// R3: BLOCK=512 (16 waves/CU, was 8), float2-interleaved LDS (ds_read_b64),
//     sqrt-folded constants: u = (x-t)/s * sqrt(0.5*log2e), e = exp2(-u^2),
//     term = (u^2 - C1) * e * (ww*MEX_C/C1).  6 VALU + 1 trans + 1 LDS / eval.

#define D_DIM 128
#define O_DIM 128
#define ROWS  16     // rows per block
#define BLOCK 512    // 8 waves: o = tid&127, group g = tid>>7 (4 rows each)

#define C1     0.72134752f   // 0.5*log2(e); exp(-z^2/2) = exp2(-C1*z^2)
#define SQRT_C 0.84932180f   // sqrt(C1)
#define WWK    1.2023651f    // MEX_C / C1, MEX_C = 2/(sqrt(3)*pi^0.25)
#define LOG2E  1.44269504f

// Prep: transpose weights to [d][o] float4 {t*is2, is2, ww*WWK, bw},
// is2 = SQRT_C / (softplus(scale)+0.1)
__global__ __launch_bounds__(256) void wavekan_prep(
    const float* __restrict__ scale,
    const float* __restrict__ trans,
    const float* __restrict__ ww,
    const float* __restrict__ bw,
    float4* __restrict__ wsW)
{
    int idx = blockIdx.x * blockDim.x + threadIdx.x;   // = o*128 + d
    if (idx >= O_DIM * D_DIM) return;
    int o = idx >> 7;
    int d = idx & (D_DIM - 1);
    float sc = scale[idx];
    float sp = fmaxf(sc, 0.0f) + log1pf(__expf(-fabsf(sc)));  // stable softplus
    float is2 = SQRT_C / (sp + 0.1f);
    float4 w;
    w.x = trans[idx] * is2;
    w.y = is2;
    w.z = ww[idx] * WWK;
    w.w = bw[idx];
    wsW[d * O_DIM + o] = w;
}

template<bool USE_WS>
__global__ __launch_bounds__(BLOCK, 4) void wavekan_main(
    const float* __restrict__ x,
    const float* __restrict__ scale,
    const float* __restrict__ trans,
    const float* __restrict__ ww,
    const float* __restrict__ bw,
    const float* __restrict__ gamma,
    const float* __restrict__ beta,
    const float4* __restrict__ wsW,
    float* __restrict__ out,
    int N)
{
    __shared__ float2 s_lr[ROWS * D_DIM];   // {layernormed, raw} interleaved

    const int tid  = threadIdx.x;
    const int row0 = blockIdx.x * ROWS;

    // ---- Phase 1: 512 threads load 16 rows x 128, LayerNorm, stage LDS ----
    {
        const int r  = tid >> 5;        // local row 0..15 (32 lanes per row)
        const int j  = tid & 31;        // lane within row
        const int d0 = j * 4;           // 4 elems per lane
        const int grow = row0 + r;

        float4 v4 = make_float4(0.f, 0.f, 0.f, 0.f);
        if (grow < N)
            v4 = *reinterpret_cast<const float4*>(x + (size_t)grow * D_DIM + d0);
        float v[4] = {v4.x, v4.y, v4.z, v4.w};

        float sum = 0.0f, ssq = 0.0f;
        #pragma unroll
        for (int k = 0; k < 4; ++k) { sum += v[k]; ssq += v[k] * v[k]; }
        #pragma unroll
        for (int m = 1; m < 32; m <<= 1) {   // reduce across the 32-lane row group
            sum += __shfl_xor(sum, m, 64);
            ssq += __shfl_xor(ssq, m, 64);
        }
        const float mean = sum * (1.0f / D_DIM);
        const float var  = ssq * (1.0f / D_DIM) - mean * mean;
        const float rstd = rsqrtf(var + 1e-5f);

        float4 g4 = *reinterpret_cast<const float4*>(gamma + d0);
        float4 b4 = *reinterpret_cast<const float4*>(beta + d0);
        float g[4] = {g4.x, g4.y, g4.z, g4.w};
        float b[4] = {b4.x, b4.y, b4.z, b4.w};

        #pragma unroll
        for (int k = 0; k < 4; ++k) {
            float lnv = (v[k] - mean) * rstd * g[k] + b[k];
            s_lr[r * D_DIM + d0 + k] = make_float2(lnv, v[k]);
        }
    }
    __syncthreads();

    // ---- Phase 2: thread = output column o x 4 rows ----
    const int o = tid & (O_DIM - 1);
    const int g = tid >> 7;  // row-group 0..3
    const float2* __restrict__ lr = s_lr + g * 4 * D_DIM;

    float accw[4] = {0.f, 0.f, 0.f, 0.f};
    float accb[4] = {0.f, 0.f, 0.f, 0.f};

    #pragma unroll 2
    for (int d = 0; d < D_DIM; ++d) {
        float tws, is, wwk, bwv;
        if (USE_WS) {
            float4 w = wsW[d * O_DIM + o];   // coalesced 16B/lane, L1/L2-resident
            tws = w.x; is = w.y; wwk = w.z; bwv = w.w;
        } else {
            int idx = o * D_DIM + d;
            float sc = scale[idx];
            float sp = fmaxf(sc, 0.0f) + log1pf(__expf(-fabsf(sc)));
            is  = SQRT_C / (sp + 0.1f);
            tws = trans[idx] * is;
            wwk = ww[idx] * WWK;
            bwv = bw[idx];
        }
        #pragma unroll
        for (int k = 0; k < 4; ++k) {
            float2 v = lr[k * D_DIM + d];    // ds_read_b64, wave-uniform broadcast
            float u  = fmaf(v.x, is, -tws);
            float u2 = u * u;
            float e  = __builtin_amdgcn_exp2f(-u2);
            accw[k]  = fmaf((u2 - C1) * e, wwk, accw[k]);
            accb[k]  = fmaf(v.y, bwv, accb[k]);
        }
    }

    // ---- Epilogue: out = wavelet + silu(base) ----
    #pragma unroll
    for (int k = 0; k < 4; ++k) {
        const int rr = row0 + g * 4 + k;
        if (rr < N) {
            float bsum = accb[k];
            float sig  = 1.0f / (1.0f + __builtin_amdgcn_exp2f(-LOG2E * bsum));
            out[(size_t)rr * O_DIM + o] = accw[k] + bsum * sig;
        }
    }
}

extern "C" void kernel_launch(void* const* d_in, const int* in_sizes, int n_in,
                              void* d_out, int out_size, void* d_ws, size_t ws_size,
                              hipStream_t stream) {
    const float* x     = (const float*)d_in[0];
    const float* scale = (const float*)d_in[1];
    const float* trans = (const float*)d_in[2];
    const float* ww    = (const float*)d_in[3];
    const float* bw    = (const float*)d_in[4];
    const float* gamma = (const float*)d_in[5];
    const float* beta  = (const float*)d_in[6];
    float* out = (float*)d_out;

    const int N = in_sizes[0] / D_DIM;       // 8192
    const int grid = (N + ROWS - 1) / ROWS;  // 512

    const size_t ws_needed = (size_t)O_DIM * D_DIM * sizeof(float4);  // 256 KB
    if (ws_size >= ws_needed) {
        wavekan_prep<<<(O_DIM * D_DIM + 255) / 256, 256, 0, stream>>>(
            scale, trans, ww, bw, (float4*)d_ws);
        wavekan_main<true><<<grid, BLOCK, 0, stream>>>(
            x, scale, trans, ww, bw, gamma, beta, (const float4*)d_ws, out, N);
    } else {
        wavekan_main<false><<<grid, BLOCK, 0, stream>>>(
            x, scale, trans, ww, bw, gamma, beta, nullptr, out, N);
    }
}